// Round 11
// baseline (174.264 us; speedup 1.0000x reference)
//
#include <hip/hip_runtime.h>
#include <hip/hip_bf16.h>

// QHNet block-linear layer. R11: persistent pipelined blocks at 3 blocks/CU.
// R10 (165us) math: stores+reads = 67% HBM duty at 2 blocks/CU; idle gaps
// when both blocks are in compute/scatter phases. Fix: LDS 71.7->46KB
// (4-row out tile + x dbuf) -> 3 blocks/CU, and R5-verified swapped-MFMA
// quad scatter (25 ds_write_b128/thread, XOR by row, near-zero conflicts;
// R9 measured 12.4M conflict cycles on the scalar scatter).
// Kept: persistent loop, load(t+1) issued before MFMA(t), LGKM-only
// barriers (stores fire-and-forget), nt loads/stores.

typedef short bf16x8 __attribute__((ext_vector_type(8)));
typedef float f32x4 __attribute__((ext_vector_type(4)));

#define LGKM_BARRIER()                                         \
    do {                                                       \
        asm volatile("s_waitcnt lgkmcnt(0)" ::: "memory");     \
        __builtin_amdgcn_sched_barrier(0);                     \
        __builtin_amdgcn_s_barrier();                          \
        __builtin_amdgcn_sched_barrier(0);                     \
    } while (0)

static __device__ __forceinline__ unsigned short f2bf(float f) {
    __hip_bfloat16 h = __float2bfloat16(f);
    union { __hip_bfloat16 h; unsigned short u; } cvt; cvt.h = h;
    return cvt.u;
}

// ---- weight prep: transpose to W[n][k] bf16 with scales folded -------------
__global__ void prep_w(const float* __restrict__ w,
                       unsigned short* __restrict__ w0t,
                       unsigned short* __restrict__ w1t) {
    int idx = blockIdx.x * 256 + threadIdx.x;   // 240*256 == 61440 exactly
    const float S000 = 1.0f / 128.0f;
    const float S011 = 1.0f / (128.0f * 1.7320508075688772f);
    const float S1X  = 1.0f / (64.0f * 1.7320508075688772f);
    const float S111 = 1.0f / (64.0f * 2.449489742783178f);
    if (idx < 320 * 128) {
        int n = idx >> 7, k = idx & 127;
        float v;
        if (n < 256) v = w[k * 256 + n] * S000;                 // w000[k][uv]
        else         v = w[32768 + k * 64 + (n - 256)] * S011;  // w011[k][uv]
        w0t[idx] = f2bf(v);
    } else {
        int i2 = idx - 320 * 128;
        int n = i2 >> 6, k = i2 & 63;
        float v;
        if (n < 128)      v = w[40960 + k * 128 + n] * S1X;           // w101
        else if (n < 256) v = w[49152 + k * 128 + (n - 128)] * S1X;   // w110
        else              v = w[57344 + k * 64  + (n - 256)] * S111;  // w111
        w1t[i2] = f2bf(v);
    }
}

#define GRID 768

// ---- main fused persistent kernel ------------------------------------------
// Swapped MFMA: D[n][batch]; lane holds n = base + grp*4 + {0..3}, batch = cn.
__global__ __launch_bounds__(256) void qhnet_main(
    const float* __restrict__ x_in,
    const unsigned short* __restrict__ w0t,
    const unsigned short* __restrict__ w1t,
    float* __restrict__ out,
    int ntiles)
{
    __shared__ __attribute__((aligned(16))) float smemf[4 * 1600];   // 25.6 KB
    __shared__ __attribute__((aligned(16))) unsigned short xbuf[2][16 * 320];
    f32x4* smemq = reinterpret_cast<f32x4*>(smemf);

    const int tid = threadIdx.x;
    const int lane = tid & 63;
    const int wv = tid >> 6;
    const int cn = lane & 15;       // batch row in tile
    const int grp = lane >> 4;
    const int swf = (cn & 7) << 3;
    const int g2 = grp >> 1, g1 = grp & 1;
    const int tr = cn & 3;          // out-tile row when active
    f32x4* rowq = smemq + tr * 400;

    const int c0base[5] = {wv * 64, wv * 64 + 16, wv * 64 + 32, wv * 64 + 48,
                           256 + wv * 16};
    const int c1base[5] = {wv * 32, wv * 32 + 16, 128 + wv * 32,
                           128 + wv * 32 + 16, 256 + wv * 16};

    // staging decode for the 5 per-thread quads
    int s_row[5], s_col[5];
    #pragma unroll
    for (int k = 0; k < 5; ++k) {
        int p = tid + (k << 8);
        s_row[k] = p / 80;
        s_col[k] = (p - s_row[k] * 80) * 4;
    }

    // ---- prologue: stage first tile into buf 0 ----
    int t = blockIdx.x;
    {
        const f32x4* xrow = reinterpret_cast<const f32x4*>(x_in + (size_t)t * 16 * 320);
        #pragma unroll
        for (int k = 0; k < 5; ++k) {
            f32x4 v = __builtin_nontemporal_load(&xrow[tid + (k << 8)]);
            int row = s_row[k], col = s_col[k], sw = (row & 7) << 3;
            if (col < 128) {
                ushort4 u;
                u.x = f2bf(v[0]); u.y = f2bf(v[1]); u.z = f2bf(v[2]); u.w = f2bf(v[3]);
                *reinterpret_cast<ushort4*>(&xbuf[0][row * 128 + (col ^ sw)]) = u;
            } else {
                #pragma unroll
                for (int e = 0; e < 4; ++e) {
                    int f = col - 128 + e;
                    int wi = f / 3, cm = f - wi * 3;
                    xbuf[0][2048 + cm * 1024 + row * 64 + (wi ^ sw)] = f2bf(v[e]);
                }
            }
        }
    }
    LGKM_BARRIER();

    int cur = 0;
    for (; t < ntiles; t += GRID) {
        const int b0 = t * 16;

        // --- x fragments from xbuf[cur] ---
        bf16x8 a0[4], a1[3][2];
        {
            const unsigned short* x0L = &xbuf[cur][0];
            const unsigned short* x1L = &xbuf[cur][2048];
            #pragma unroll
            for (int ks = 0; ks < 4; ++ks)
                a0[ks] = *reinterpret_cast<const bf16x8*>(
                    &x0L[cn * 128 + ((ks * 32 + grp * 8) ^ swf)]);
            #pragma unroll
            for (int c = 0; c < 3; ++c)
                #pragma unroll
                for (int ks = 0; ks < 2; ++ks)
                    a1[c][ks] = *reinterpret_cast<const bf16x8*>(
                        &x1L[c * 1024 + cn * 64 + ((ks * 32 + grp * 8) ^ swf)]);
        }

        // --- issue next tile's loads early (hide HBM latency under MFMA) ---
        const bool more = (t + GRID) < ntiles;
        f32x4 v[5];
        if (more) {
            const f32x4* xrow = reinterpret_cast<const f32x4*>(
                x_in + (size_t)(t + GRID) * 16 * 320);
            #pragma unroll
            for (int k = 0; k < 5; ++k)
                v[k] = __builtin_nontemporal_load(&xrow[tid + (k << 8)]);
        }

        // --- swapped MFMA: A = weight frag (row n), B = x frag (col batch) ---
        f32x4 acc0[5] = {};
        f32x4 acc1[3][5] = {};
        #pragma unroll
        for (int tt = 0; tt < 5; ++tt) {
            const unsigned short* wp = w0t + (c0base[tt] + cn) * 128 + grp * 8;
            #pragma unroll
            for (int ks = 0; ks < 4; ++ks) {
                bf16x8 b = *reinterpret_cast<const bf16x8*>(wp + ks * 32);
                acc0[tt] = __builtin_amdgcn_mfma_f32_16x16x32_bf16(b, a0[ks], acc0[tt], 0, 0, 0);
            }
        }
        #pragma unroll
        for (int tt = 0; tt < 5; ++tt) {
            const unsigned short* wp = w1t + (c1base[tt] + cn) * 64 + grp * 8;
            #pragma unroll
            for (int ks = 0; ks < 2; ++ks) {
                bf16x8 b = *reinterpret_cast<const bf16x8*>(wp + ks * 32);
                #pragma unroll
                for (int c = 0; c < 3; ++c)
                    acc1[c][tt] = __builtin_amdgcn_mfma_f32_16x16x32_bf16(b, a1[c][ks], acc1[c][tt], 0, 0, 0);
            }
        }

        // --- write next tile's staging (loads had MFMA-time to land) ---
        if (more) {
            const int nb = cur ^ 1;
            #pragma unroll
            for (int k = 0; k < 5; ++k) {
                int row = s_row[k], col = s_col[k], sw = (row & 7) << 3;
                if (col < 128) {
                    ushort4 u;
                    u.x = f2bf(v[k][0]); u.y = f2bf(v[k][1]);
                    u.z = f2bf(v[k][2]); u.w = f2bf(v[k][3]);
                    *reinterpret_cast<ushort4*>(&xbuf[nb][row * 128 + (col ^ sw)]) = u;
                } else {
                    #pragma unroll
                    for (int e = 0; e < 4; ++e) {
                        int f = col - 128 + e;
                        int wi = f / 3, cm = f - wi * 3;
                        xbuf[nb][2048 + cm * 1024 + row * 64 + (wi ^ sw)] = f2bf(v[k][e]);
                    }
                }
            }
        }
        LGKM_BARRIER();   // staging(t+1) visible; frag-reads(t) done; prev copy done

        // --- epilogue: 4 phases x 4 batch rows; quad scatter -> nt copy ---
        #pragma unroll
        for (int h = 0; h < 4; ++h) {
            if (h) LGKM_BARRIER();          // prev copy's LDS reads done
            if ((cn >> 2) == h) {
                #pragma unroll
                for (int tt = 0; tt < 4; ++tt) {            // blk00
                    int q = (wv * 4 + tt) * 10 + grp;
                    rowq[q ^ tr] = acc0[tt];
                }
                #pragma unroll
                for (int tt = 0; tt < 2; ++tt) {            // blk01: 3 quads
                    int u01 = 4 * wv + 2 * tt + g2;
                    int q0 = u01 * 10 + 4 + 3 * g1;
                    f32x4 qa = {acc1[0][tt][0], acc1[1][tt][0], acc1[2][tt][0], acc1[0][tt][1]};
                    f32x4 qb = {acc1[1][tt][1], acc1[2][tt][1], acc1[0][tt][2], acc1[1][tt][2]};
                    f32x4 qc = {acc1[2][tt][2], acc1[0][tt][3], acc1[1][tt][3], acc1[2][tt][3]};
                    rowq[q0 ^ tr]       = qa;
                    rowq[(q0 + 1) ^ tr] = qb;
                    rowq[(q0 + 2) ^ tr] = qc;
                }
                #pragma unroll
                for (int tt = 0; tt < 2; ++tt) {            // blk10
                    int rr = 16 + 3 * (2 * wv + tt);
                    #pragma unroll
                    for (int c = 0; c < 3; ++c) {
                        int q = (rr + c) * 10 + grp;
                        rowq[q ^ tr] = acc1[c][tt + 2];
                    }
                }
                {                                           // blk11: 9 quads
                    int rr = 16 + 3 * (2 * wv + g2);
                    int cq = 4 + 3 * g1;
                    f32x4 d = acc0[4];
                    f32x4 t0 = acc1[0][4], t1 = acc1[1][4], t2 = acc1[2][4];
                    f32x4 q00 = {d[0], t2[0], -t1[0], d[1]};
                    f32x4 q01 = {t2[1], -t1[1], d[2], t2[2]};
                    f32x4 q02 = {-t1[2], d[3], t2[3], -t1[3]};
                    f32x4 q10 = {-t2[0], d[0], t0[0], -t2[1]};
                    f32x4 q11 = {d[1], t0[1], -t2[2], d[2]};
                    f32x4 q12 = {t0[2], -t2[3], d[3], t0[3]};
                    f32x4 q20 = {t1[0], -t0[0], d[0], t1[1]};
                    f32x4 q21 = {-t0[1], d[1], t1[2], -t0[2]};
                    f32x4 q22 = {d[2], t1[3], -t0[3], d[3]};
                    rowq[(rr * 10 + cq)            ^ tr] = q00;
                    rowq[(rr * 10 + cq + 1)        ^ tr] = q01;
                    rowq[(rr * 10 + cq + 2)        ^ tr] = q02;
                    rowq[((rr + 1) * 10 + cq)      ^ tr] = q10;
                    rowq[((rr + 1) * 10 + cq + 1)  ^ tr] = q11;
                    rowq[((rr + 1) * 10 + cq + 2)  ^ tr] = q12;
                    rowq[((rr + 2) * 10 + cq)      ^ tr] = q20;
                    rowq[((rr + 2) * 10 + cq + 1)  ^ tr] = q21;
                    rowq[((rr + 2) * 10 + cq + 2)  ^ tr] = q22;
                }
            }
            LGKM_BARRIER();                 // scatter visible
            // coalesced nt copy-out: 4 rows = 1600 quads
            float* dstf = out + (size_t)(b0 + h * 4) * 1600;
            #pragma unroll
            for (int k = 0; k < 7; ++k) {
                int p = tid + (k << 8);
                if (k < 6 || tid < 64) {
                    int row = p / 400;
                    int q = p - row * 400;
                    f32x4 val = smemq[row * 400 + (q ^ row)];
                    __builtin_nontemporal_store(
                        val, reinterpret_cast<f32x4*>(dstf + (size_t)p * 4));
                }
            }
        }
        cur ^= 1;
    }
}

extern "C" void kernel_launch(void* const* d_in, const int* in_sizes, int n_in,
                              void* d_out, int out_size, void* d_ws, size_t ws_size,
                              hipStream_t stream) {
    const float* x_in = (const float*)d_in[0];
    const float* weights = (const float*)d_in[1];
    float* out = (float*)d_out;
    unsigned short* w0t = (unsigned short*)d_ws;            // 320*128 bf16
    unsigned short* w1t = w0t + 320 * 128;                  // 320*64  bf16
    int B = in_sizes[0] / 320;                              // 100000

    prep_w<<<240, 256, 0, stream>>>(weights, w0t, w1t);
    qhnet_main<<<GRID, 256, 0, stream>>>(x_in, w0t, w1t, out, B / 16);
}

// Round 12
// 164.766 us; speedup vs baseline: 1.0576x; 1.0576x over previous
//
#include <hip/hip_runtime.h>
#include <hip/hip_bf16.h>

// QHNet block-linear layer. R12: R10 persistent structure (2 blocks/CU,
// GRID 512, x dbuf staging, prefetch-before-MFMA, LGKM-only barriers, nt
// loads/stores) + overlapped double-buffered epilogue: 4 phases x 4 rows,
// scatter(h+1)->buf[(h+1)&1] issued alongside copy(h)->out from buf[h&1].
// Scatter hidden under copy; stores spread into 4 bursts/tile (R10 issued
// 2 big bursts -> store queue drained dry between them, 70% write duty).
// Same barrier count as R10 (4 LGKM/tile; post-cp3 hazard covered by the
// next tile's staging barrier). Quad scatter (R11-verified math): 25
// ds_write_b128 per active lane vs ~100 ds_write_b32.

typedef short bf16x8 __attribute__((ext_vector_type(8)));
typedef float f32x4 __attribute__((ext_vector_type(4)));

#define LGKM_BARRIER()                                         \
    do {                                                       \
        asm volatile("s_waitcnt lgkmcnt(0)" ::: "memory");     \
        __builtin_amdgcn_sched_barrier(0);                     \
        __builtin_amdgcn_s_barrier();                          \
        __builtin_amdgcn_sched_barrier(0);                     \
    } while (0)

static __device__ __forceinline__ unsigned short f2bf(float f) {
    __hip_bfloat16 h = __float2bfloat16(f);
    union { __hip_bfloat16 h; unsigned short u; } cvt; cvt.h = h;
    return cvt.u;
}

// ---- weight prep: transpose to W[n][k] bf16 with scales folded -------------
__global__ void prep_w(const float* __restrict__ w,
                       unsigned short* __restrict__ w0t,
                       unsigned short* __restrict__ w1t) {
    int idx = blockIdx.x * 256 + threadIdx.x;   // 240*256 == 61440 exactly
    const float S000 = 1.0f / 128.0f;
    const float S011 = 1.0f / (128.0f * 1.7320508075688772f);
    const float S1X  = 1.0f / (64.0f * 1.7320508075688772f);
    const float S111 = 1.0f / (64.0f * 2.449489742783178f);
    if (idx < 320 * 128) {
        int n = idx >> 7, k = idx & 127;
        float v;
        if (n < 256) v = w[k * 256 + n] * S000;                 // w000[k][uv]
        else         v = w[32768 + k * 64 + (n - 256)] * S011;  // w011[k][uv]
        w0t[idx] = f2bf(v);
    } else {
        int i2 = idx - 320 * 128;
        int n = i2 >> 6, k = i2 & 63;
        float v;
        if (n < 128)      v = w[40960 + k * 128 + n] * S1X;           // w101
        else if (n < 256) v = w[49152 + k * 128 + (n - 128)] * S1X;   // w110
        else              v = w[57344 + k * 64  + (n - 256)] * S111;  // w111
        w1t[i2] = f2bf(v);
    }
}

#define GRID 512

// ---- main fused persistent kernel ------------------------------------------
// Swapped MFMA: D[n][batch]; lane holds n = base + grp*4 + {0..3}, batch = cn.
__global__ __launch_bounds__(256) void qhnet_main(
    const float* __restrict__ x_in,
    const unsigned short* __restrict__ w0t,
    const unsigned short* __restrict__ w1t,
    float* __restrict__ out,
    int ntiles)
{
    // out staging: 2 x 4-row buffers (dbuf) = 51.2 KB; x dbuf 20.5 KB.
    __shared__ __attribute__((aligned(16))) float smemf[2 * 4 * 1600];
    __shared__ __attribute__((aligned(16))) unsigned short xbuf[2][16 * 320];
    f32x4* smemq = reinterpret_cast<f32x4*>(smemf);     // [2][4*400]

    const int tid = threadIdx.x;
    const int lane = tid & 63;
    const int wv = tid >> 6;
    const int cn = lane & 15;       // batch row in tile
    const int grp = lane >> 4;
    const int swf = (cn & 7) << 3;
    const int g2 = grp >> 1, g1 = grp & 1;
    const int tr = cn & 3;          // out-tile row when scatter-active
    const int scph = cn >> 2;       // scatter phase this lane serves

    const int c0base[5] = {wv * 64, wv * 64 + 16, wv * 64 + 32, wv * 64 + 48,
                           256 + wv * 16};
    const int c1base[5] = {wv * 32, wv * 32 + 16, 128 + wv * 32,
                           128 + wv * 32 + 16, 256 + wv * 16};

    // staging decode for the 5 per-thread quads
    int s_row[5], s_col[5];
    #pragma unroll
    for (int k = 0; k < 5; ++k) {
        int p = tid + (k << 8);
        s_row[k] = p / 80;
        s_col[k] = (p - s_row[k] * 80) * 4;
    }

    // ---- prologue: stage first tile into xbuf[0] ----
    int t = blockIdx.x;
    {
        const f32x4* xrow = reinterpret_cast<const f32x4*>(x_in + (size_t)t * 16 * 320);
        #pragma unroll
        for (int k = 0; k < 5; ++k) {
            f32x4 v = __builtin_nontemporal_load(&xrow[tid + (k << 8)]);
            int row = s_row[k], col = s_col[k], sw = (row & 7) << 3;
            if (col < 128) {
                ushort4 u;
                u.x = f2bf(v[0]); u.y = f2bf(v[1]); u.z = f2bf(v[2]); u.w = f2bf(v[3]);
                *reinterpret_cast<ushort4*>(&xbuf[0][row * 128 + (col ^ sw)]) = u;
            } else {
                #pragma unroll
                for (int e = 0; e < 4; ++e) {
                    int f = col - 128 + e;
                    int wi = f / 3, cm = f - wi * 3;
                    xbuf[0][2048 + cm * 1024 + row * 64 + (wi ^ sw)] = f2bf(v[e]);
                }
            }
        }
    }
    LGKM_BARRIER();

    int cur = 0;
    for (; t < ntiles; t += GRID) {
        const int b0 = t * 16;

        // --- x fragments from xbuf[cur] ---
        bf16x8 a0[4], a1[3][2];
        {
            const unsigned short* x0L = &xbuf[cur][0];
            const unsigned short* x1L = &xbuf[cur][2048];
            #pragma unroll
            for (int ks = 0; ks < 4; ++ks)
                a0[ks] = *reinterpret_cast<const bf16x8*>(
                    &x0L[cn * 128 + ((ks * 32 + grp * 8) ^ swf)]);
            #pragma unroll
            for (int c = 0; c < 3; ++c)
                #pragma unroll
                for (int ks = 0; ks < 2; ++ks)
                    a1[c][ks] = *reinterpret_cast<const bf16x8*>(
                        &x1L[c * 1024 + cn * 64 + ((ks * 32 + grp * 8) ^ swf)]);
        }

        // --- issue next tile's loads early (hide HBM latency under MFMA) ---
        const bool more = (t + GRID) < ntiles;
        f32x4 v[5];
        if (more) {
            const f32x4* xrow = reinterpret_cast<const f32x4*>(
                x_in + (size_t)(t + GRID) * 16 * 320);
            #pragma unroll
            for (int k = 0; k < 5; ++k)
                v[k] = __builtin_nontemporal_load(&xrow[tid + (k << 8)]);
        }

        // --- swapped MFMA: A = weight frag (row n), B = x frag (col batch) ---
        f32x4 acc0[5] = {};
        f32x4 acc1[3][5] = {};
        #pragma unroll
        for (int tt = 0; tt < 5; ++tt) {
            const unsigned short* wp = w0t + (c0base[tt] + cn) * 128 + grp * 8;
            #pragma unroll
            for (int ks = 0; ks < 4; ++ks) {
                bf16x8 b = *reinterpret_cast<const bf16x8*>(wp + ks * 32);
                acc0[tt] = __builtin_amdgcn_mfma_f32_16x16x32_bf16(b, a0[ks], acc0[tt], 0, 0, 0);
            }
        }
        #pragma unroll
        for (int tt = 0; tt < 5; ++tt) {
            const unsigned short* wp = w1t + (c1base[tt] + cn) * 64 + grp * 8;
            #pragma unroll
            for (int ks = 0; ks < 2; ++ks) {
                bf16x8 b = *reinterpret_cast<const bf16x8*>(wp + ks * 32);
                #pragma unroll
                for (int c = 0; c < 3; ++c)
                    acc1[c][tt] = __builtin_amdgcn_mfma_f32_16x16x32_bf16(b, a1[c][ks], acc1[c][tt], 0, 0, 0);
            }
        }

        // --- write next tile's staging (loads had MFMA-time to land) ---
        if (more) {
            const int nb = cur ^ 1;
            #pragma unroll
            for (int k = 0; k < 5; ++k) {
                int row = s_row[k], col = s_col[k], sw = (row & 7) << 3;
                if (col < 128) {
                    ushort4 u;
                    u.x = f2bf(v[k][0]); u.y = f2bf(v[k][1]);
                    u.z = f2bf(v[k][2]); u.w = f2bf(v[k][3]);
                    *reinterpret_cast<ushort4*>(&xbuf[nb][row * 128 + (col ^ sw)]) = u;
                } else {
                    #pragma unroll
                    for (int e = 0; e < 4; ++e) {
                        int f = col - 128 + e;
                        int wi = f / 3, cm = f - wi * 3;
                        xbuf[nb][2048 + cm * 1024 + row * 64 + (wi ^ sw)] = f2bf(v[k][e]);
                    }
                }
            }
        }

        // --- overlapped epilogue: 4 phases x 4 rows, out-tile dbuf ---
        // scatter(h) helper expanded inline; active lanes: scph == h.
        // Phase flow: sc0 (pre-barrier, overlaps staging); BAR;
        //   { sc(h+1) || copy(h) ; BAR } for h=0..2; copy(3) (no BAR --
        //   next tile's staging barrier covers cp3's reads before sc1(t+1)).
        #pragma unroll
        for (int h = 0; h < 5; ++h) {
            if (h > 0) {
                // copy(h-1): 1600 quads from buf (h-1)&1
                const f32x4* src = smemq + ((h - 1) & 1) * 1600;
                float* dstf = out + (size_t)(b0 + (h - 1) * 4) * 1600;
                #pragma unroll
                for (int k = 0; k < 7; ++k) {
                    int p = tid + (k << 8);
                    if (k < 6 || tid < 64) {
                        int row = p / 400;
                        int q = p - row * 400;
                        f32x4 val = src[row * 400 + (q ^ row)];
                        __builtin_nontemporal_store(
                            val, reinterpret_cast<f32x4*>(dstf + (size_t)p * 4));
                    }
                }
            }
            if (h < 4 && scph == h) {
                // scatter(h) into buf h&1 (R11-verified quad layout)
                f32x4* rowq = smemq + (h & 1) * 1600 + tr * 400;
                #pragma unroll
                for (int tt = 0; tt < 4; ++tt) {            // blk00
                    int q = (wv * 4 + tt) * 10 + grp;
                    rowq[q ^ tr] = acc0[tt];
                }
                #pragma unroll
                for (int tt = 0; tt < 2; ++tt) {            // blk01: 3 quads
                    int u01 = 4 * wv + 2 * tt + g2;
                    int q0 = u01 * 10 + 4 + 3 * g1;
                    f32x4 qa = {acc1[0][tt][0], acc1[1][tt][0], acc1[2][tt][0], acc1[0][tt][1]};
                    f32x4 qb = {acc1[1][tt][1], acc1[2][tt][1], acc1[0][tt][2], acc1[1][tt][2]};
                    f32x4 qc = {acc1[2][tt][2], acc1[0][tt][3], acc1[1][tt][3], acc1[2][tt][3]};
                    rowq[q0 ^ tr]       = qa;
                    rowq[(q0 + 1) ^ tr] = qb;
                    rowq[(q0 + 2) ^ tr] = qc;
                }
                #pragma unroll
                for (int tt = 0; tt < 2; ++tt) {            // blk10
                    int rr = 16 + 3 * (2 * wv + tt);
                    #pragma unroll
                    for (int c = 0; c < 3; ++c) {
                        int q = (rr + c) * 10 + grp;
                        rowq[q ^ tr] = acc1[c][tt + 2];
                    }
                }
                {                                           // blk11: 9 quads
                    int rr = 16 + 3 * (2 * wv + g2);
                    int cq = 4 + 3 * g1;
                    f32x4 d = acc0[4];
                    f32x4 t0 = acc1[0][4], t1 = acc1[1][4], t2 = acc1[2][4];
                    f32x4 q00 = {d[0], t2[0], -t1[0], d[1]};
                    f32x4 q01 = {t2[1], -t1[1], d[2], t2[2]};
                    f32x4 q02 = {-t1[2], d[3], t2[3], -t1[3]};
                    f32x4 q10 = {-t2[0], d[0], t0[0], -t2[1]};
                    f32x4 q11 = {d[1], t0[1], -t2[2], d[2]};
                    f32x4 q12 = {t0[2], -t2[3], d[3], t0[3]};
                    f32x4 q20 = {t1[0], -t0[0], d[0], t1[1]};
                    f32x4 q21 = {-t0[1], d[1], t1[2], -t0[2]};
                    f32x4 q22 = {d[2], t1[3], -t0[3], d[3]};
                    rowq[(rr * 10 + cq)            ^ tr] = q00;
                    rowq[(rr * 10 + cq + 1)        ^ tr] = q01;
                    rowq[(rr * 10 + cq + 2)        ^ tr] = q02;
                    rowq[((rr + 1) * 10 + cq)      ^ tr] = q10;
                    rowq[((rr + 1) * 10 + cq + 1)  ^ tr] = q11;
                    rowq[((rr + 1) * 10 + cq + 2)  ^ tr] = q12;
                    rowq[((rr + 2) * 10 + cq)      ^ tr] = q20;
                    rowq[((rr + 2) * 10 + cq + 1)  ^ tr] = q21;
                    rowq[((rr + 2) * 10 + cq + 2)  ^ tr] = q22;
                }
            }
            if (h < 4) LGKM_BARRIER();  // staging+sc0 (h=0) / cpN+sc(N+1) visible
        }
        cur ^= 1;
    }
}

extern "C" void kernel_launch(void* const* d_in, const int* in_sizes, int n_in,
                              void* d_out, int out_size, void* d_ws, size_t ws_size,
                              hipStream_t stream) {
    const float* x_in = (const float*)d_in[0];
    const float* weights = (const float*)d_in[1];
    float* out = (float*)d_out;
    unsigned short* w0t = (unsigned short*)d_ws;            // 320*128 bf16
    unsigned short* w1t = w0t + 320 * 128;                  // 320*64  bf16
    int B = in_sizes[0] / 320;                              // 100000

    prep_w<<<240, 256, 0, stream>>>(weights, w0t, w1t);
    qhnet_main<<<GRID, 256, 0, stream>>>(x_in, w0t, w1t, out, B / 16);
}